// Round 6
// baseline (199.687 us; speedup 1.0000x reference)
//
#include <hip/hip_runtime.h>
#include <math.h>

#define NROWS 4000000
#define DCOV  64
#define NSEG  100000

#define SEGS_PER_WAVE   8
#define WAVES_PER_BLOCK 4
#define SEGS_PER_BLOCK  (SEGS_PER_WAVE * WAVES_PER_BLOCK)   // 32
#define NBLOCKS         (NSEG / SEGS_PER_BLOCK)             // 3125
#define WCAP            1024   // per-wave LDS logit slots (mean 320 rows, sigma ~18)

typedef float f32x4 __attribute__((ext_vector_type(4)));

// 64-lane cooperative lower_bound over sorted seg[0..NROWS): 64-ary search.
__device__ __forceinline__ int lower_bound_seg(const int* __restrict__ seg,
                                               int target, int lane) {
    int lo = 0, n = NROWS;
    while (n > 64) {
        const int step = (n + 63) >> 6;                 // ceil(n/64)
        const long long p = (long long)lo + (long long)(lane + 1) * step;
        const bool lt = (p < (long long)lo + n) && (seg[p] < target);
        const int cnt = (int)__popcll(__ballot(lt));    // lanes with lt form a prefix
        lo += cnt * step;
        n = min(step, n - cnt * step);
    }
    const bool lt = (lane < n) && (seg[lo + lane] < target);
    return lo + (int)__popcll(__ballot(lt));
}

// ---------------------------------------------------------------------------
// Fully wave-owned fused kernel — ZERO __syncthreads. Wave gw owns segments
// [gw*8, gw*8+8) end-to-end:
//   1. two 64-ary searches -> the wave's contiguous row range
//   2. gap-filled segment starts into the wave's private LDS st slice
//   3. logits = X@w + b into the wave's private LDS slice (16 lanes/row, x4)
//   4. per-segment softmax, nontemporal stores straight to out
// Waves never wait on each other: softmax/search of one wave overlaps the
// X-streaming of the other 31 waves on the CU. Never-taken global fallback
// (nrows > WCAP) keeps correctness for adversarial inputs.
// ---------------------------------------------------------------------------
__global__ __launch_bounds__(256, 8)
void fused_clr_kernel(const float* __restrict__ X,
                      const int* __restrict__ seg,
                      const float* __restrict__ w,
                      const float* __restrict__ b,
                      float* __restrict__ out,
                      float* __restrict__ gl /* global logits fallback */) {
    __shared__ float logit_lds[WAVES_PER_BLOCK][WCAP];
    __shared__ int   st_lds[WAVES_PER_BLOCK][SEGS_PER_WAVE + 1];

    const int tid  = threadIdx.x;
    const int lane = tid & 63;
    const int wv   = tid >> 6;          // wave in block, 0..3
    const int sub  = lane & 15;         // position in the row's 16-lane team
    const int rig  = lane >> 4;         // row within 4-row group

    const int gw  = blockIdx.x * WAVES_PER_BLOCK + wv;
    const int ws0 = gw * SEGS_PER_WAVE;
    const int ws1 = ws0 + SEGS_PER_WAVE;

    float* __restrict__ wlds = logit_lds[wv];
    int*   __restrict__ wst  = st_lds[wv];

    // ---- 1: the wave's row range ----
    const int row_start = lower_bound_seg(seg, ws0, lane);
    const int row_end   = lower_bound_seg(seg, ws1, lane);
    const int nrows     = row_end - row_start;

    const bool  use_lds = (nrows <= WCAP);
    const float bias    = b[0];
    const float4 w4     = reinterpret_cast<const float4*>(w)[sub];
    const f32x4* Xv     = reinterpret_cast<const f32x4*>(X);

    // ---- 2: segment starts, gap-filled (exactly one writer per entry) ----
    if (nrows == 0) {
        if (lane <= SEGS_PER_WAVE) wst[lane] = row_end;
    } else {
        for (int i = row_start + lane; i < row_end; i += 64) {
            const int s    = seg[i];
            const int prev = (i == row_start) ? (ws0 - 1) : seg[i - 1];
            for (int t = prev + 1; t <= s; ++t) wst[t - ws0] = i;
            if (i == row_end - 1) {
                for (int t = s + 1; t <= ws1; ++t) wst[t - ws0] = row_end;
            }
        }
    }

    // ---- 3: logits, 16 rows per iteration (4 nontemporal loads in flight) ----
    for (int rb = row_start; rb < row_end; rb += 16) {
        const int r0 = rb + rig, r1 = rb + 4 + rig, r2 = rb + 8 + rig, r3 = rb + 12 + rig;
        f32x4 x0 = {0,0,0,0}, x1 = {0,0,0,0}, x2 = {0,0,0,0}, x3 = {0,0,0,0};
        const f32x4* xp = Xv + (long long)rb * 16 + lane;
        if (r0 < row_end) x0 = __builtin_nontemporal_load(xp);
        if (r1 < row_end) x1 = __builtin_nontemporal_load(xp + 64);
        if (r2 < row_end) x2 = __builtin_nontemporal_load(xp + 128);
        if (r3 < row_end) x3 = __builtin_nontemporal_load(xp + 192);
        float p0 = x0.x * w4.x + x0.y * w4.y + x0.z * w4.z + x0.w * w4.w;
        float p1 = x1.x * w4.x + x1.y * w4.y + x1.z * w4.z + x1.w * w4.w;
        float p2 = x2.x * w4.x + x2.y * w4.y + x2.z * w4.z + x2.w * w4.w;
        float p3 = x3.x * w4.x + x3.y * w4.y + x3.z * w4.z + x3.w * w4.w;
        #pragma unroll
        for (int m = 1; m < 16; m <<= 1) {      // 16-lane team reduce
            p0 += __shfl_xor(p0, m);
            p1 += __shfl_xor(p1, m);
            p2 += __shfl_xor(p2, m);
            p3 += __shfl_xor(p3, m);
        }
        if (sub == 0) {
            if (use_lds) {
                if (r0 < row_end) wlds[r0 - row_start] = p0 + bias;
                if (r1 < row_end) wlds[r1 - row_start] = p1 + bias;
                if (r2 < row_end) wlds[r2 - row_start] = p2 + bias;
                if (r3 < row_end) wlds[r3 - row_start] = p3 + bias;
            } else {
                if (r0 < row_end) gl[r0] = p0 + bias;
                if (r1 < row_end) gl[r1] = p1 + bias;
                if (r2 < row_end) gl[r2] = p2 + bias;
                if (r3 < row_end) gl[r3] = p3 + bias;
            }
        }
    }
    if (!use_lds) __threadfence_block();   // never-taken path: drain gl writes

    // ---- 4: per-segment softmax, direct nontemporal writes to out ----
    for (int j = 0; j < SEGS_PER_WAVE; ++j) {
        const int a0  = wst[j];
        const int a1  = wst[j + 1];
        const int len = a1 - a0;
        if (len <= 0) continue;                 // wave-uniform
        if (len <= 64) {
            const bool act = lane < len;
            const int  idx = a0 - row_start + lane;
            float x = act ? (use_lds ? wlds[idx] : gl[a0 + lane]) : -INFINITY;
            float mx = x;
            #pragma unroll
            for (int m = 1; m < 64; m <<= 1) mx = fmaxf(mx, __shfl_xor(mx, m));
            float e = act ? __expf(x - mx) : 0.0f;
            float sum = e;
            #pragma unroll
            for (int m = 1; m < 64; m <<= 1) sum += __shfl_xor(sum, m);
            if (act) __builtin_nontemporal_store(e / sum, &out[a0 + lane]);
        } else {
            float mx = -INFINITY;
            for (int i = a0 + lane; i < a1; i += 64)
                mx = fmaxf(mx, use_lds ? wlds[i - row_start] : gl[i]);
            #pragma unroll
            for (int m = 1; m < 64; m <<= 1) mx = fmaxf(mx, __shfl_xor(mx, m));
            float sum = 0.0f;
            for (int i = a0 + lane; i < a1; i += 64)
                sum += __expf((use_lds ? wlds[i - row_start] : gl[i]) - mx);
            #pragma unroll
            for (int m = 1; m < 64; m <<= 1) sum += __shfl_xor(sum, m);
            const float inv = 1.0f / sum;
            for (int i = a0 + lane; i < a1; i += 64) {
                float pr = __expf((use_lds ? wlds[i - row_start] : gl[i]) - mx) * inv;
                __builtin_nontemporal_store(pr, &out[i]);
            }
        }
    }
}

extern "C" void kernel_launch(void* const* d_in, const int* in_sizes, int n_in,
                              void* d_out, int out_size, void* d_ws, size_t ws_size,
                              hipStream_t stream) {
    const float* X   = (const float*)d_in[0];
    const int*   seg = (const int*)d_in[1];
    const float* w   = (const float*)d_in[2];
    const float* b   = (const float*)d_in[3];
    float*       out = (float*)d_out;
    float*       gl  = (float*)d_ws;    // fallback logits buffer (normally unused)

    fused_clr_kernel<<<NBLOCKS, 256, 0, stream>>>(X, seg, w, b, out, gl);
}

// Round 7
// 182.146 us; speedup vs baseline: 1.0963x; 1.0963x over previous
//
#include <hip/hip_runtime.h>
#include <math.h>

#define NROWS 4000000
#define DCOV  64
#define NSEG  100000

#define SEGS_PER_BLOCK 25
#define NBLOCKS (NSEG / SEGS_PER_BLOCK)   // 4000
#define CAP 2048                          // LDS logit slots (mean rows/block ~1000, sigma ~32)

typedef float f32x4 __attribute__((ext_vector_type(4)));

// 64-lane cooperative lower_bound over sorted seg[0..NROWS): 64-ary search,
// 4 rounds of parallel probes instead of ~22 serial dependent loads.
__device__ __forceinline__ int lower_bound_seg(const int* __restrict__ seg,
                                               int target, int lane) {
    int lo = 0, n = NROWS;
    while (n > 64) {
        const int step = (n + 63) >> 6;                 // ceil(n/64)
        const long long p = (long long)lo + (long long)(lane + 1) * step;
        const bool lt = (p < (long long)lo + n) && (seg[p] < target);
        const int cnt = (int)__popcll(__ballot(lt));    // lanes with lt form a prefix
        lo += cnt * step;
        n = min(step, n - cnt * step);
    }
    const bool lt = (lane < n) && (seg[lo + lane] < target);
    return lo + (int)__popcll(__ballot(lt));
}

// ---------------------------------------------------------------------------
// Single fused kernel, 2 barriers per block (R4 structure — best measured).
// Block b owns segments [b*25, b*25+25):
//   phase 0 : wave-parallel 64-ary search for the block's row range  | barrier
//   phase 1 : gap-filled segment starts into LDS, then logits = X@w+b
//             straight into LDS (wave-coop, 16 lanes/row, x4 unroll) | barrier
//   phase 2 : per-wave softmax over a CONTIGUOUS run of segments,
//             plain cached stores to out (L2 merges partial lines)
// Fallback (never expected: nrows > CAP) routes logits via global d_ws.
// ---------------------------------------------------------------------------
__global__ __launch_bounds__(256, 8)
void fused_clr_kernel(const float* __restrict__ X,
                      const int* __restrict__ seg,
                      const float* __restrict__ w,
                      const float* __restrict__ b,
                      float* __restrict__ out,
                      float* __restrict__ gl /* global logits fallback */) {
    __shared__ int   st_lds[SEGS_PER_BLOCK + 1];
    __shared__ float logit_lds[CAP];
    __shared__ int   rs_sh, re_sh;

    const int tid  = threadIdx.x;
    const int lane = tid & 63;
    const int wv   = tid >> 6;          // wave in block, 0..3
    const int sub  = lane & 15;         // position in the row's 16-lane team
    const int rig  = lane >> 4;         // row within 4-row group

    const int s0 = blockIdx.x * SEGS_PER_BLOCK;
    const int s1 = s0 + SEGS_PER_BLOCK;

    // ---- phase 0: row range (waves 0 and 1 search concurrently) ----
    if (wv == 0) {
        int r = lower_bound_seg(seg, s0, lane);
        if (lane == 0) rs_sh = r;
    } else if (wv == 1) {
        int r = lower_bound_seg(seg, s1, lane);
        if (lane == 0) re_sh = r;
    }
    __syncthreads();
    const int row_start = rs_sh;
    const int row_end   = re_sh;
    const int nrows     = row_end - row_start;

    const bool  use_lds = (nrows <= CAP);
    const float bias    = b[0];
    const float4 w4     = reinterpret_cast<const float4*>(w)[sub];
    const f32x4* Xv     = reinterpret_cast<const f32x4*>(X);

    // ---- phase 1a: segment starts, gap-filled (each entry has exactly one
    //      writer: the first row i with seg[i] >= t). Tail entries filled by
    //      the owner of the last row. ----
    if (nrows == 0) {
        if (tid <= SEGS_PER_BLOCK) st_lds[tid] = row_end;
    } else {
        for (int i = row_start + tid; i < row_end; i += 256) {
            const int s    = seg[i];
            const int prev = (i == row_start) ? (s0 - 1) : seg[i - 1];
            for (int t = prev + 1; t <= s; ++t) st_lds[t - s0] = i;
            if (i == row_end - 1) {
                for (int t = s + 1; t <= s1; ++t) st_lds[t - s0] = row_end;
            }
        }
    }

    // ---- phase 1b: logits, 16 rows per wave per iteration (4 loads in flight) ----
    for (int rb = row_start + wv * 16; rb < row_end; rb += 64) {
        const int r0 = rb + rig, r1 = rb + 4 + rig, r2 = rb + 8 + rig, r3 = rb + 12 + rig;
        f32x4 x0 = {0,0,0,0}, x1 = {0,0,0,0}, x2 = {0,0,0,0}, x3 = {0,0,0,0};
        const f32x4* xp = Xv + (long long)rb * 16 + lane;
        if (r0 < row_end) x0 = __builtin_nontemporal_load(xp);
        if (r1 < row_end) x1 = __builtin_nontemporal_load(xp + 64);
        if (r2 < row_end) x2 = __builtin_nontemporal_load(xp + 128);
        if (r3 < row_end) x3 = __builtin_nontemporal_load(xp + 192);
        float p0 = x0.x * w4.x + x0.y * w4.y + x0.z * w4.z + x0.w * w4.w;
        float p1 = x1.x * w4.x + x1.y * w4.y + x1.z * w4.z + x1.w * w4.w;
        float p2 = x2.x * w4.x + x2.y * w4.y + x2.z * w4.z + x2.w * w4.w;
        float p3 = x3.x * w4.x + x3.y * w4.y + x3.z * w4.z + x3.w * w4.w;
        #pragma unroll
        for (int m = 1; m < 16; m <<= 1) {      // 16-lane team reduce
            p0 += __shfl_xor(p0, m);
            p1 += __shfl_xor(p1, m);
            p2 += __shfl_xor(p2, m);
            p3 += __shfl_xor(p3, m);
        }
        if (sub == 0) {
            if (use_lds) {
                if (r0 < row_end) logit_lds[r0 - row_start] = p0 + bias;
                if (r1 < row_end) logit_lds[r1 - row_start] = p1 + bias;
                if (r2 < row_end) logit_lds[r2 - row_start] = p2 + bias;
                if (r3 < row_end) logit_lds[r3 - row_start] = p3 + bias;
            } else {
                if (r0 < row_end) gl[r0] = p0 + bias;
                if (r1 < row_end) gl[r1] = p1 + bias;
                if (r2 < row_end) gl[r2] = p2 + bias;
                if (r3 < row_end) gl[r3] = p3 + bias;
            }
        }
    }
    __syncthreads();

    // ---- phase 2: per-segment softmax; each wave owns a CONTIGUOUS run of
    //      segments (sequential store stream), plain cached stores ----
    const int q = SEGS_PER_BLOCK / 4;           // 6
    const int r = SEGS_PER_BLOCK % 4;           // 1
    const int jbeg = wv * q + min(wv, r);
    const int jend = jbeg + q + (wv < r ? 1 : 0);
    for (int j = jbeg; j < jend; ++j) {
        const int a0  = st_lds[j];
        const int a1  = st_lds[j + 1];
        const int len = a1 - a0;
        if (len <= 0) continue;                 // wave-uniform
        if (len <= 64) {
            const bool act = lane < len;
            const int  idx = a0 - row_start + lane;
            float x = act ? (use_lds ? logit_lds[idx] : gl[a0 + lane]) : -INFINITY;
            float mx = x;
            #pragma unroll
            for (int m = 1; m < 64; m <<= 1) mx = fmaxf(mx, __shfl_xor(mx, m));
            float e = act ? __expf(x - mx) : 0.0f;
            float sum = e;
            #pragma unroll
            for (int m = 1; m < 64; m <<= 1) sum += __shfl_xor(sum, m);
            if (act) out[a0 + lane] = e / sum;
        } else {
            float mx = -INFINITY;
            for (int i = a0 + lane; i < a1; i += 64)
                mx = fmaxf(mx, use_lds ? logit_lds[i - row_start] : gl[i]);
            #pragma unroll
            for (int m = 1; m < 64; m <<= 1) mx = fmaxf(mx, __shfl_xor(mx, m));
            float sum = 0.0f;
            for (int i = a0 + lane; i < a1; i += 64)
                sum += __expf((use_lds ? logit_lds[i - row_start] : gl[i]) - mx);
            #pragma unroll
            for (int m = 1; m < 64; m <<= 1) sum += __shfl_xor(sum, m);
            const float inv = 1.0f / sum;
            for (int i = a0 + lane; i < a1; i += 64) {
                float pr = __expf((use_lds ? logit_lds[i - row_start] : gl[i]) - mx) * inv;
                out[i] = pr;
            }
        }
    }
}

extern "C" void kernel_launch(void* const* d_in, const int* in_sizes, int n_in,
                              void* d_out, int out_size, void* d_ws, size_t ws_size,
                              hipStream_t stream) {
    const float* X   = (const float*)d_in[0];
    const int*   seg = (const int*)d_in[1];
    const float* w   = (const float*)d_in[2];
    const float* b   = (const float*)d_in[3];
    float*       out = (float*)d_out;
    float*       gl  = (float*)d_ws;    // fallback logits buffer (normally unused)

    fused_clr_kernel<<<NBLOCKS, 256, 0, stream>>>(X, seg, w, b, out, gl);
}